// Round 3
// baseline (2170.064 us; speedup 1.0000x reference)
//
#include <hip/hip_runtime.h>
#include <hip/hip_bf16.h>

// Problem: STN  B=16, H=W=256, C=32, FILTER=64 (f4=16, f2=32)
//
// Workspace layout (floats):
//   p1    : 16*127*127*16 = 4,129,024
//   p2    : 16* 62* 62*32 = 1,968,128
//   p3    : 16* 30* 30*32 =   460,800
//   theta : 16*6          =        96

#define P1_ELEMS 4129024
#define P2_ELEMS 1968128
#define P3_ELEMS 460800

// ---------------------------------------------------------------- conv+pool
// Block = 256 thr = 4 waves. Tile = 8 pooled rows x 16 pooled cols
// (= 16x32 conv px). Each lane owns a VERTICAL conv-pixel pair (both rows of
// one pooled row) x ALL F filters:
//   - weight fetch amortization 1 s_load_dwordx4 : 8 v_fmac (was 1:4 -> the
//     lgkmcnt(0) drains between SMEM weight batches and FMAs were the 44%
//     stall in the previous version)
//   - vertical pool is in-lane; only horizontal pool needs shfl_xor(1).
//
// Input patch 18 rows x 34 cols. CH=32 won't fit (78 KB), so channels are
// staged in PHASES=CH/16 phases of 4 float4-planes (16 ch) into a 39.3 KB
// buffer -> 4 blocks/CU (50% occupancy, was 31%).
//
// LDS: plane stride 614 float4 -> plane bank starts {0,24,16,8} mod 32 and
// 8-thread b128 groups hit disjoint banks for BOTH staging writes
// (ch4-fastest) and compute reads (px-consecutive). Conflict-free.

#define FMA4(A, S, W) \
    A.x += (S) * (W).x; A.y += (S) * (W).y; \
    A.z += (S) * (W).z; A.w += (S) * (W).w;

template<int CH, int F, int IN_HW, int POOL_HW>
__global__ __launch_bounds__(256, 4) void conv_pool_kernel(
    const float* __restrict__ in, const float* __restrict__ Wt,
    const float* __restrict__ bias, float* __restrict__ out)
{
    constexpr int PHASES = CH / 16;             // 2 for CH=32, 1 for CH=16
    constexpr int PSTR   = 614;                 // float4 per plane (612 + pad)
    __shared__ float4 xt[4 * PSTR];             // 39,296 B

    const int tid = threadIdx.x;
    const int b   = blockIdx.z;
    const int r0  = blockIdx.y * 16;            // conv/input row origin
    const int c0  = blockIdx.x * 32;            // conv/input col origin
    const float* ib = in + (size_t)b * (IN_HW * IN_HW * CH);

    const int wv   = tid >> 6;
    const int lane = tid & 63;
    const int prow = lane >> 5;                 // which pooled row of the wave
    const int ccol = lane & 31;                 // conv col within tile
    const int pr   = 2 * wv + prow;             // pooled row within tile (0..7)
    const int px0  = (2 * pr) * 34 + ccol;      // upper conv px of the pair

    float4 accA[F / 4], accB[F / 4];            // rows 2*pr and 2*pr+1
    #pragma unroll
    for (int q = 0; q < F / 4; ++q) {
        const float4 bv = *(const float4*)(bias + 4 * q);
        accA[q] = bv; accB[q] = bv;
    }

    #pragma unroll 1
    for (int ph = 0; ph < PHASES; ++ph) {
        if (ph) __syncthreads();                // prev compute done before overwrite

        // ---- stage 18x34 px x 16 ch (4 planes), ch4-fastest (coalesced) ----
        for (int idx = tid; idx < 612 * 4; idx += 256) {
            const int ch4 = idx & 3;
            const int px  = idx >> 2;
            const int dr  = px / 34;
            const int j   = px - dr * 34;
            int r = r0 + dr; if (r > IN_HW - 1) r = IN_HW - 1;
            int c = c0 + j;  if (c > IN_HW - 1) c = IN_HW - 1;
            xt[ch4 * PSTR + px] =
                *(const float4*)(ib + ((size_t)r * IN_HW + c) * CH + (ph * 4 + ch4) * 4);
        }
        __syncthreads();

        #pragma unroll 1
        for (int kh = 0; kh < 3; ++kh) {
          #pragma unroll 1
          for (int kw = 0; kw < 3; ++kw) {
            const float* wp = Wt + ((kh * 3 + kw) * CH + ph * 16) * F;  // uniform
            const int px = px0 + kh * 34 + kw;
            #pragma unroll
            for (int c4 = 0; c4 < 4; ++c4) {
                const float4 xA = xt[c4 * PSTR + px];        // row 2*pr + kh
                const float4 xB = xt[c4 * PSTR + px + 34];   // row 2*pr + 1 + kh
                #pragma unroll
                for (int cc = 0; cc < 4; ++cc) {
                    const float xa = (cc == 0) ? xA.x : (cc == 1) ? xA.y
                                   : (cc == 2) ? xA.z : xA.w;
                    const float xb = (cc == 0) ? xB.x : (cc == 1) ? xB.y
                                   : (cc == 2) ? xB.z : xB.w;
                    const float* wr = wp + (4 * c4 + cc) * F;
                    #pragma unroll
                    for (int q = 0; q < F / 4; ++q) {
                        const float4 w4 = *(const float4*)(wr + 4 * q);  // s_load
                        FMA4(accA[q], xa, w4)
                        FMA4(accB[q], xb, w4)
                    }
                }
            }
          }
        }
    }

    // ---- 2x2 max-pool (vertical in-lane, horizontal via shfl) + ReLU ----
    #pragma unroll
    for (int q = 0; q < F / 4; ++q) {
        float4 v;
        v.x = fmaxf(accA[q].x, accB[q].x);
        v.y = fmaxf(accA[q].y, accB[q].y);
        v.z = fmaxf(accA[q].z, accB[q].z);
        v.w = fmaxf(accA[q].w, accB[q].w);
        v.x = fmaxf(fmaxf(v.x, __shfl_xor(v.x, 1)), 0.0f);
        v.y = fmaxf(fmaxf(v.y, __shfl_xor(v.y, 1)), 0.0f);
        v.z = fmaxf(fmaxf(v.z, __shfl_xor(v.z, 1)), 0.0f);
        v.w = fmaxf(fmaxf(v.w, __shfl_xor(v.w, 1)), 0.0f);
        accA[q] = v;
    }

    const int prg = blockIdx.y * 8 + pr;
    const int pcg = blockIdx.x * 16 + (ccol >> 1);
    if (!(ccol & 1) && prg < POOL_HW && pcg < POOL_HW) {
        float* dst = out + (((size_t)b * POOL_HW + prg) * POOL_HW + pcg) * F;
        #pragma unroll
        for (int q = 0; q < F / 4; ++q) *(float4*)(dst + 4 * q) = accA[q];
    }
}

// ----------------------------------------------------------------- head
// Coalesced float4 mean reduction (the old scalar 900-iter strided loop was
// latency-bound): 256 thr = 32 px-slots x 8 ch4-quads, contiguous 4 KB per
// iteration.
__global__ __launch_bounds__(256) void head_kernel(
    const float* __restrict__ p3,
    const float* __restrict__ D1, const float* __restrict__ db1,
    const float* __restrict__ D2, const float* __restrict__ db2,
    const float* __restrict__ D3, const float* __restrict__ db3,
    float* __restrict__ theta)
{
    __shared__ float4 red[32][8];
    __shared__ float hmean[32];
    __shared__ float h1[64];
    __shared__ float h2[32];

    const int b   = blockIdx.x;
    const int tid = threadIdx.x;
    const int slot = tid >> 3, ch4 = tid & 7;

    const float* p = p3 + (size_t)b * (900 * 32);
    float4 s; s.x = 0.0f; s.y = 0.0f; s.z = 0.0f; s.w = 0.0f;
    for (int i = slot; i < 900; i += 32) {
        const float4 v = *(const float4*)(p + i * 32 + ch4 * 4);
        s.x += v.x; s.y += v.y; s.z += v.z; s.w += v.w;
    }
    red[slot][ch4] = s;
    __syncthreads();

    if (tid < 8) {
        float4 m; m.x = 0.0f; m.y = 0.0f; m.z = 0.0f; m.w = 0.0f;
        #pragma unroll
        for (int j = 0; j < 32; ++j) {
            const float4 v = red[j][tid];
            m.x += v.x; m.y += v.y; m.z += v.z; m.w += v.w;
        }
        hmean[tid * 4 + 0] = m.x * (1.0f / 900.0f);
        hmean[tid * 4 + 1] = m.y * (1.0f / 900.0f);
        hmean[tid * 4 + 2] = m.z * (1.0f / 900.0f);
        hmean[tid * 4 + 3] = m.w * (1.0f / 900.0f);
    }
    __syncthreads();

    if (tid < 64) {
        float a = db1[tid];
        #pragma unroll
        for (int k = 0; k < 32; ++k) a += hmean[k] * D1[k * 64 + tid];
        h1[tid] = fmaxf(a, 0.0f);
    }
    __syncthreads();

    if (tid < 32) {
        float a = db2[tid];
        #pragma unroll
        for (int k = 0; k < 64; ++k) a += h1[k] * D2[k * 32 + tid];
        h2[tid] = fmaxf(a, 0.0f);
    }
    __syncthreads();

    if (tid < 6) {
        float a = db3[tid];
        #pragma unroll
        for (int k = 0; k < 32; ++k) a += h2[k] * D3[k * 6 + tid];
        theta[b * 6 + tid] = a;
    }
}

// ----------------------------------------------------------------- sampler
__global__ __launch_bounds__(256) void sampler_kernel(
    const float* __restrict__ x, const float* __restrict__ theta,
    float* __restrict__ out)
{
    const int t  = blockIdx.x * 256 + threadIdx.x;
    const int c4 = t & 7;
    const int w  = (t >> 3) & 255;
    const int h  = (t >> 11) & 255;
    const int b  = t >> 19;

    const float* th = theta + b*6;
    const float gx = -1.0f + (float)w * (2.0f / 255.0f);
    const float gy = -1.0f + (float)h * (2.0f / 255.0f);
    const float xS = th[0]*gx + th[1]*gy + th[2];
    const float yS = th[3]*gx + th[4]*gy + th[5];
    const float xp = 0.5f * (xS + 1.0f) * 254.0f;
    const float yp = 0.5f * (yS + 1.0f) * 254.0f;

    int x0 = (int)floorf(xp), y0 = (int)floorf(yp);
    int x1 = x0 + 1,          y1 = y0 + 1;
    x0 = x0 < 0 ? 0 : (x0 > 255 ? 255 : x0);
    x1 = x1 < 0 ? 0 : (x1 > 255 ? 255 : x1);
    y0 = y0 < 0 ? 0 : (y0 > 255 ? 255 : y0);
    y1 = y1 < 0 ? 0 : (y1 > 255 ? 255 : y1);

    const float x0f = (float)x0, x1f = (float)x1;
    const float y0f = (float)y0, y1f = (float)y1;
    const float wa = (x1f - xp) * (y1f - yp);
    const float wb = (x1f - xp) * (yp - y0f);
    const float wc = (xp - x0f) * (y1f - yp);
    const float wd = (xp - x0f) * (yp - y0f);

    const float* xb = x + (size_t)b * (256*256*32) + c4*4;
    const float4 Ia = *(const float4*)(xb + ((size_t)y0*256 + x0)*32);
    const float4 Ib = *(const float4*)(xb + ((size_t)y1*256 + x0)*32);
    const float4 Ic = *(const float4*)(xb + ((size_t)y0*256 + x1)*32);
    const float4 Id = *(const float4*)(xb + ((size_t)y1*256 + x1)*32);

    float4 o;
    o.x = wa*Ia.x + wb*Ib.x + wc*Ic.x + wd*Id.x;
    o.y = wa*Ia.y + wb*Ib.y + wc*Ic.y + wd*Id.y;
    o.z = wa*Ia.z + wb*Ib.z + wc*Ic.z + wd*Id.z;
    o.w = wa*Ia.w + wb*Ib.w + wc*Ic.w + wd*Id.w;
    ((float4*)out)[t] = o;
}

// ----------------------------------------------------------------- launch
extern "C" void kernel_launch(void* const* d_in, const int* in_sizes, int n_in,
                              void* d_out, int out_size, void* d_ws, size_t ws_size,
                              hipStream_t stream) {
    const float* x   = (const float*)d_in[0];
    const float* W1  = (const float*)d_in[1];
    const float* b1  = (const float*)d_in[2];
    const float* W2  = (const float*)d_in[3];
    const float* b2  = (const float*)d_in[4];
    const float* W3  = (const float*)d_in[5];
    const float* b3  = (const float*)d_in[6];
    const float* D1  = (const float*)d_in[7];
    const float* db1 = (const float*)d_in[8];
    const float* D2  = (const float*)d_in[9];
    const float* db2 = (const float*)d_in[10];
    const float* D3  = (const float*)d_in[11];
    const float* db3 = (const float*)d_in[12];
    float* out = (float*)d_out;

    float* p1    = (float*)d_ws;
    float* p2    = p1 + P1_ELEMS;
    float* p3    = p2 + P2_ELEMS;
    float* theta = p3 + P3_ELEMS;

    // Pooled tile 8 rows x 16 cols per block:
    conv_pool_kernel<32, 16, 256, 127><<<dim3(8, 16, 16), 256, 0, stream>>>(x,  W1, b1, p1);
    conv_pool_kernel<16, 32, 127,  62><<<dim3(4,  8, 16), 256, 0, stream>>>(p1, W2, b2, p2);
    conv_pool_kernel<32, 32,  62,  30><<<dim3(2,  4, 16), 256, 0, stream>>>(p2, W3, b3, p3);
    head_kernel      <<<dim3(16),    256, 0, stream>>>(p3, D1, db1, D2, db2, D3, db3, theta);
    sampler_kernel   <<<dim3(32768), 256, 0, stream>>>(x, theta, out);
}

// Round 4
// 474.764 us; speedup vs baseline: 4.5708x; 4.5708x over previous
//
#include <hip/hip_runtime.h>
#include <hip/hip_bf16.h>

// Problem: STN  B=16, H=W=256, C=32, FILTER=64 (f4=16, f2=32)
//
// Workspace layout (floats):
//   p1    : 16*127*127*16 = 4,129,024
//   p2    : 16* 62* 62*32 = 1,968,128
//   p3    : 16* 30* 30*32 =   460,800
//   theta : 16*6          =        96

#define P1_ELEMS 4129024
#define P2_ELEMS 1968128
#define P3_ELEMS 460800

// ---------------------------------------------------------------- conv+pool
// Round-2 proven structure: block = 256 thr = 4 waves; tile = 4 pooled rows
// x 16 pooled cols = 8x32 conv px; ONE conv pixel per lane, FB filters per
// lane (acc = FB/4 float4 <= 32 VGPRs -> no spill; round-3's 2px/lane +
// launch_bounds(256,4) spilled: WRITE_SIZE 967 MB scratch, occupancy 6%).
//
// New vs round 2:
//  * channel-phased staging: always 4 float4-planes (16 ch) in LDS,
//    PHASES=CH/16 -> LDS 21.8 KB (was 43.6) -> 7 blocks/CU, occupancy
//    cap 31% -> ~80%. Cross-block phase skew lets FMA waves cover other
//    waves' SMEM-weight lgkmcnt drains (the 44% stall at 2.5 waves/SIMD).
//  * filter-split (FB < F) for conv3: grid 256 -> 1024 blocks (was 1
//    block/CU, pure latency).
//
// LDS: plane stride 341 float4 (1364 dw, 1364 mod 32 = 20) -> plane bank
// starts {0,20,8,28} distinct mod 32; staging writes (ch4-fastest) and
// compute reads (px-consecutive) both conflict-free (measured 0 in r2).
// Weights are wave-uniform -> s_load, SGPR operand in v_fmac.

#define FMA4(A, S, W) \
    A.x += (S) * (W).x; A.y += (S) * (W).y; \
    A.z += (S) * (W).z; A.w += (S) * (W).w;

template<int CH, int F, int FB, int IN_HW, int POOL_HW>
__global__ __launch_bounds__(256) void conv_pool_kernel(
    const float* __restrict__ in, const float* __restrict__ Wt,
    const float* __restrict__ bias, float* __restrict__ out)
{
    constexpr int PHASES = CH / 16;             // 2 for CH=32, 1 for CH=16
    constexpr int NSPLIT = F / FB;              // filter groups across blocks
    constexpr int PSTR   = 341;                 // float4 per plane (340 + 1)
    __shared__ float4 xt[4 * PSTR];             // 21,824 B

    const int tid   = threadIdx.x;
    const int b     = blockIdx.z;
    const int split = (NSPLIT > 1) ? (int)(blockIdx.x % NSPLIT) : 0;
    const int tx    = (NSPLIT > 1) ? (int)(blockIdx.x / NSPLIT) : (int)blockIdx.x;
    const int f0    = split * FB;
    const int r0    = blockIdx.y * 8;           // conv/input row origin
    const int c0    = tx * 32;                  // conv/input col origin
    const float* ib = in + (size_t)b * (IN_HW * IN_HW * CH);

    const int wv   = tid >> 6;
    const int lane = tid & 63;
    const int ccol = lane & 31;                          // conv col in tile
    const int px0  = (2 * wv + (lane >> 5)) * 34 + ccol; // conv px in plane

    float4 acc[FB / 4];
    #pragma unroll
    for (int q = 0; q < FB / 4; ++q)
        acc[q] = *(const float4*)(bias + f0 + 4 * q);

    #pragma unroll 1
    for (int ph = 0; ph < PHASES; ++ph) {
        if (ph) __syncthreads();                // drain prev compute reads

        // ---- stage 10x34 px x 16 ch (4 planes), ch4-fastest ----
        for (int idx = tid; idx < 340 * 4; idx += 256) {
            const int ch4 = idx & 3;
            const int px  = idx >> 2;
            const int dr  = px / 34;
            const int j   = px - dr * 34;
            int r = r0 + dr; if (r > IN_HW - 1) r = IN_HW - 1;
            int c = c0 + j;  if (c > IN_HW - 1) c = IN_HW - 1;
            xt[ch4 * PSTR + px] =
                *(const float4*)(ib + ((size_t)r * IN_HW + c) * CH + ph * 16 + ch4 * 4);
        }
        __syncthreads();

        #pragma unroll 1
        for (int kh = 0; kh < 3; ++kh) {
          #pragma unroll 1
          for (int kw = 0; kw < 3; ++kw) {
            const float* wp = Wt + ((kh * 3 + kw) * CH + ph * 16) * F + f0; // uniform
            const int px = px0 + kh * 34 + kw;
            #pragma unroll
            for (int c4 = 0; c4 < 4; ++c4) {
                const float4 xv = xt[c4 * PSTR + px];
                #pragma unroll
                for (int cc = 0; cc < 4; ++cc) {
                    const float xc = (cc == 0) ? xv.x : (cc == 1) ? xv.y
                                   : (cc == 2) ? xv.z : xv.w;
                    const float* wr = wp + (4 * c4 + cc) * F;
                    #pragma unroll
                    for (int q = 0; q < FB / 4; ++q) {
                        const float4 w4 = *(const float4*)(wr + 4 * q);  // s_load
                        FMA4(acc[q], xc, w4)
                    }
                }
            }
          }
        }
    }

    // ---- 2x2 max-pool across lanes + ReLU ----
    #pragma unroll
    for (int q = 0; q < FB / 4; ++q) {
        float4 v = acc[q];
        v.x = fmaxf(v.x, __shfl_xor(v.x, 1));
        v.y = fmaxf(v.y, __shfl_xor(v.y, 1));
        v.z = fmaxf(v.z, __shfl_xor(v.z, 1));
        v.w = fmaxf(v.w, __shfl_xor(v.w, 1));
        v.x = fmaxf(fmaxf(v.x, __shfl_xor(v.x, 32)), 0.0f);
        v.y = fmaxf(fmaxf(v.y, __shfl_xor(v.y, 32)), 0.0f);
        v.z = fmaxf(fmaxf(v.z, __shfl_xor(v.z, 32)), 0.0f);
        v.w = fmaxf(fmaxf(v.w, __shfl_xor(v.w, 32)), 0.0f);
        acc[q] = v;
    }

    const int pr = blockIdx.y * 4 + wv;
    const int pc = tx * 16 + (ccol >> 1);
    if ((lane & 1) == 0 && lane < 32 && pr < POOL_HW && pc < POOL_HW) {
        float* dst = out + (((size_t)b * POOL_HW + pr) * POOL_HW + pc) * F + f0;
        #pragma unroll
        for (int q = 0; q < FB / 4; ++q) *(float4*)(dst + 4 * q) = acc[q];
    }
}

// ----------------------------------------------------------------- head
// Coalesced float4 mean reduction: 256 thr = 32 px-slots x 8 ch4-quads,
// contiguous 4 KB per iteration.
__global__ __launch_bounds__(256) void head_kernel(
    const float* __restrict__ p3,
    const float* __restrict__ D1, const float* __restrict__ db1,
    const float* __restrict__ D2, const float* __restrict__ db2,
    const float* __restrict__ D3, const float* __restrict__ db3,
    float* __restrict__ theta)
{
    __shared__ float4 red[32][8];
    __shared__ float hmean[32];
    __shared__ float h1[64];
    __shared__ float h2[32];

    const int b   = blockIdx.x;
    const int tid = threadIdx.x;
    const int slot = tid >> 3, ch4 = tid & 7;

    const float* p = p3 + (size_t)b * (900 * 32);
    float4 s; s.x = 0.0f; s.y = 0.0f; s.z = 0.0f; s.w = 0.0f;
    for (int i = slot; i < 900; i += 32) {
        const float4 v = *(const float4*)(p + i * 32 + ch4 * 4);
        s.x += v.x; s.y += v.y; s.z += v.z; s.w += v.w;
    }
    red[slot][ch4] = s;
    __syncthreads();

    if (tid < 8) {
        float4 m; m.x = 0.0f; m.y = 0.0f; m.z = 0.0f; m.w = 0.0f;
        #pragma unroll
        for (int j = 0; j < 32; ++j) {
            const float4 v = red[j][tid];
            m.x += v.x; m.y += v.y; m.z += v.z; m.w += v.w;
        }
        hmean[tid * 4 + 0] = m.x * (1.0f / 900.0f);
        hmean[tid * 4 + 1] = m.y * (1.0f / 900.0f);
        hmean[tid * 4 + 2] = m.z * (1.0f / 900.0f);
        hmean[tid * 4 + 3] = m.w * (1.0f / 900.0f);
    }
    __syncthreads();

    if (tid < 64) {
        float a = db1[tid];
        #pragma unroll
        for (int k = 0; k < 32; ++k) a += hmean[k] * D1[k * 64 + tid];
        h1[tid] = fmaxf(a, 0.0f);
    }
    __syncthreads();

    if (tid < 32) {
        float a = db2[tid];
        #pragma unroll
        for (int k = 0; k < 64; ++k) a += h1[k] * D2[k * 32 + tid];
        h2[tid] = fmaxf(a, 0.0f);
    }
    __syncthreads();

    if (tid < 6) {
        float a = db3[tid];
        #pragma unroll
        for (int k = 0; k < 32; ++k) a += h2[k] * D3[k * 6 + tid];
        theta[b * 6 + tid] = a;
    }
}

// ----------------------------------------------------------------- sampler
__global__ __launch_bounds__(256) void sampler_kernel(
    const float* __restrict__ x, const float* __restrict__ theta,
    float* __restrict__ out)
{
    const int t  = blockIdx.x * 256 + threadIdx.x;
    const int c4 = t & 7;
    const int w  = (t >> 3) & 255;
    const int h  = (t >> 11) & 255;
    const int b  = t >> 19;

    const float* th = theta + b*6;
    const float gx = -1.0f + (float)w * (2.0f / 255.0f);
    const float gy = -1.0f + (float)h * (2.0f / 255.0f);
    const float xS = th[0]*gx + th[1]*gy + th[2];
    const float yS = th[3]*gx + th[4]*gy + th[5];
    const float xp = 0.5f * (xS + 1.0f) * 254.0f;
    const float yp = 0.5f * (yS + 1.0f) * 254.0f;

    int x0 = (int)floorf(xp), y0 = (int)floorf(yp);
    int x1 = x0 + 1,          y1 = y0 + 1;
    x0 = x0 < 0 ? 0 : (x0 > 255 ? 255 : x0);
    x1 = x1 < 0 ? 0 : (x1 > 255 ? 255 : x1);
    y0 = y0 < 0 ? 0 : (y0 > 255 ? 255 : y0);
    y1 = y1 < 0 ? 0 : (y1 > 255 ? 255 : y1);

    const float x0f = (float)x0, x1f = (float)x1;
    const float y0f = (float)y0, y1f = (float)y1;
    const float wa = (x1f - xp) * (y1f - yp);
    const float wb = (x1f - xp) * (yp - y0f);
    const float wc = (xp - x0f) * (y1f - yp);
    const float wd = (xp - x0f) * (yp - y0f);

    const float* xb = x + (size_t)b * (256*256*32) + c4*4;
    const float4 Ia = *(const float4*)(xb + ((size_t)y0*256 + x0)*32);
    const float4 Ib = *(const float4*)(xb + ((size_t)y1*256 + x0)*32);
    const float4 Ic = *(const float4*)(xb + ((size_t)y0*256 + x1)*32);
    const float4 Id = *(const float4*)(xb + ((size_t)y1*256 + x1)*32);

    float4 o;
    o.x = wa*Ia.x + wb*Ib.x + wc*Ic.x + wd*Id.x;
    o.y = wa*Ia.y + wb*Ib.y + wc*Ic.y + wd*Id.y;
    o.z = wa*Ia.z + wb*Ib.z + wc*Ic.z + wd*Id.z;
    o.w = wa*Ia.w + wb*Ib.w + wc*Ic.w + wd*Id.w;
    ((float4*)out)[t] = o;
}

// ----------------------------------------------------------------- launch
extern "C" void kernel_launch(void* const* d_in, const int* in_sizes, int n_in,
                              void* d_out, int out_size, void* d_ws, size_t ws_size,
                              hipStream_t stream) {
    const float* x   = (const float*)d_in[0];
    const float* W1  = (const float*)d_in[1];
    const float* b1  = (const float*)d_in[2];
    const float* W2  = (const float*)d_in[3];
    const float* b2  = (const float*)d_in[4];
    const float* W3  = (const float*)d_in[5];
    const float* b3  = (const float*)d_in[6];
    const float* D1  = (const float*)d_in[7];
    const float* db1 = (const float*)d_in[8];
    const float* D2  = (const float*)d_in[9];
    const float* db2 = (const float*)d_in[10];
    const float* D3  = (const float*)d_in[11];
    const float* db3 = (const float*)d_in[12];
    float* out = (float*)d_out;

    float* p1    = (float*)d_ws;
    float* p2    = p1 + P1_ELEMS;
    float* p3    = p2 + P2_ELEMS;
    float* theta = p3 + P3_ELEMS;

    // <CH, F, FB, IN_HW, POOL_HW>; pooled tile 4x16 per block; grid.x = tiles_x * (F/FB)
    conv_pool_kernel<32, 16, 16, 256, 127><<<dim3(8, 32, 16), 256, 0, stream>>>(x,  W1, b1, p1);
    conv_pool_kernel<16, 32, 32, 127,  62><<<dim3(4, 16, 16), 256, 0, stream>>>(p1, W2, b2, p2);
    conv_pool_kernel<32, 32,  8,  62,  30><<<dim3(8,  8, 16), 256, 0, stream>>>(p2, W3, b3, p3);
    head_kernel      <<<dim3(16),    256, 0, stream>>>(p3, D1, db1, D2, db2, D3, db3, theta);
    sampler_kernel   <<<dim3(32768), 256, 0, stream>>>(x, theta, out);
}